// Round 1
// baseline (803.713 us; speedup 1.0000x reference)
//
#include <hip/hip_runtime.h>
#include <stdint.h>

#define N_TOK 131072
#define KC    512
#define DIM   128
#define LOGK  6.2383246250395075f
#define CLIP_HI 0.99999988079071044921875f  /* fp32(float64(1.0-1e-7)) */
#define CLIP_LO 1.17549435e-38f

typedef float  f32x4 __attribute__((ext_vector_type(4)));
typedef short  s16x8 __attribute__((ext_vector_type(8)));

__device__ __forceinline__ unsigned short f2bf(float f) {
  unsigned int b = __float_as_uint(f);
  b = b + 0x7FFFu + ((b >> 16) & 1u);   // RNE to bf16
  return (unsigned short)(b >> 16);
}

// ---- prep: embedding -> bf16 row-major [K][D], bf16 transposed [D][K], row norms
__global__ void prep_kernel(const float* __restrict__ emb,
                            unsigned short* __restrict__ E_hi,
                            unsigned short* __restrict__ ET_hi,
                            float* __restrict__ normE) {
  int k = blockIdx.x;    // 512
  int d = threadIdx.x;   // 128
  float v = emb[k * DIM + d];
  unsigned short h = f2bf(v);
  E_hi[k * DIM + d]  = h;
  ET_hi[d * KC + k]  = h;
  __shared__ float red[128];
  red[d] = v * v;
  __syncthreads();
  for (int s = 64; s > 0; s >>= 1) { if (d < s) red[d] += red[d + s]; __syncthreads(); }
  if (d == 0) normE[k] = red[0];
}

// ---- main fused kernel: 128 threads (2 waves), 32 tokens per block
__global__ __launch_bounds__(128, 2) void vq_main(
    const float* __restrict__ X, const float* __restrict__ U,
    const unsigned short* __restrict__ E_hi, const unsigned short* __restrict__ ET_hi,
    const float* __restrict__ normE,
    float* __restrict__ out_q, float* __restrict__ out_enc,
    float* __restrict__ avgp_rep, float* __restrict__ kl_rep)
{
  const int tid  = threadIdx.x;
  const int w    = tid >> 6;        // wave id 0..1
  const int lane = tid & 63;
  const int q    = lane >> 4;       // quad 0..3
  const int c0   = lane & 15;
  const int wg   = blockIdx.x;
  const int rowbase = wg * 32 + w * 16;   // wave's 16 token rows

  __shared__ float avgp[KC];
  __shared__ unsigned short encT[2][16][520];   // per-wave 16x512 bf16, +8 pad

  for (int i = tid; i < KC; i += 128) avgp[i] = 0.f;
  __syncthreads();

  // ================= Phase A: S = X * E^T (bf16 MFMA), l = 2S - ||e||^2 ========
  s16x8 afrag[4];
  {
    const float* xrow = X + (size_t)(rowbase + c0) * DIM;  // A: m = lane&15
    #pragma unroll
    for (int db = 0; db < 4; db++) {
      const float4 v0 = *reinterpret_cast<const float4*>(xrow + db * 32 + q * 8);
      const float4 v1 = *reinterpret_cast<const float4*>(xrow + db * 32 + q * 8 + 4);
      s16x8 u8;
      u8[0] = (short)f2bf(v0.x); u8[1] = (short)f2bf(v0.y);
      u8[2] = (short)f2bf(v0.z); u8[3] = (short)f2bf(v0.w);
      u8[4] = (short)f2bf(v1.x); u8[5] = (short)f2bf(v1.y);
      u8[6] = (short)f2bf(v1.z); u8[7] = (short)f2bf(v1.w);
      afrag[db] = u8;
    }
  }

  f32x4 acc[32];   // C-layout: col(code)=nt*16+c0, row(token)=q*4+reg
  #pragma unroll
  for (int nt = 0; nt < 32; nt++) {
    f32x4 a = {0.f, 0.f, 0.f, 0.f};
    #pragma unroll
    for (int db = 0; db < 4; db++) {
      s16x8 b = *reinterpret_cast<const s16x8*>(E_hi + (nt * 16 + c0) * DIM + db * 32 + q * 8);
      a = __builtin_amdgcn_mfma_f32_16x16x32_bf16(afrag[db], b, a, 0, 0, 0);
    }
    acc[nt] = a;
  }
  #pragma unroll
  for (int nt = 0; nt < 32; nt++) {
    float ne = normE[nt * 16 + c0];
    acc[nt] = acc[nt] * 2.f - ne;   // logits (row-shifted; softmax-invariant)
  }

  // ================= Phase B: softmax stats, KL, gumbel, encodings =============
  float kl_acc = 0.f;
  float avg_acc[32];
  #pragma unroll
  for (int nt = 0; nt < 32; nt++) avg_acc[nt] = 0.f;

  #pragma unroll
  for (int r = 0; r < 4; r++) {
    const int grow = rowbase + q * 4 + r;

    float m1 = -3.4e38f;
    #pragma unroll
    for (int nt = 0; nt < 32; nt++) m1 = fmaxf(m1, acc[nt][r]);
    #pragma unroll
    for (int m = 1; m <= 8; m <<= 1) m1 = fmaxf(m1, __shfl_xor(m1, m));

    float Z1 = 0.f, W = 0.f;
    #pragma unroll
    for (int nt = 0; nt < 32; nt++) {
      float dd = acc[nt][r] - m1;
      float e  = __expf(dd);
      Z1 += e; W = fmaf(e, dd, W);
    }
    #pragma unroll
    for (int m = 1; m <= 8; m <<= 1) { Z1 += __shfl_xor(Z1, m); W += __shfl_xor(W, m); }
    kl_acc += W / Z1 - logf(Z1) + LOGK;   // sum_k p*(logp+logK)

    // gumbel; overwrite logits with y = 2*(l+g)
    const float* urow = U + (size_t)grow * KC;
    #pragma unroll
    for (int nt = 0; nt < 32; nt++) {
      float uv = urow[nt * 16 + c0];
      uv = fminf(fmaxf(uv, CLIP_LO), CLIP_HI);
      float g = -logf(-logf(uv));        // precise log: hw log unsafe near u~1
      acc[nt][r] = 2.f * (acc[nt][r] + g);
    }
    float m2 = -3.4e38f;
    #pragma unroll
    for (int nt = 0; nt < 32; nt++) m2 = fmaxf(m2, acc[nt][r]);
    #pragma unroll
    for (int m = 1; m <= 8; m <<= 1) m2 = fmaxf(m2, __shfl_xor(m2, m));
    float Z2 = 0.f;
    #pragma unroll
    for (int nt = 0; nt < 32; nt++) {
      float e2 = __expf(acc[nt][r] - m2);
      acc[nt][r] = e2;
      Z2 += e2;
    }
    #pragma unroll
    for (int m = 1; m <= 8; m <<= 1) Z2 += __shfl_xor(Z2, m);
    const float rz = 1.0f / Z2;

    float* erow = out_enc + (size_t)grow * KC;
    #pragma unroll
    for (int nt = 0; nt < 32; nt++) {
      float enc = acc[nt][r] * rz;
      erow[nt * 16 + c0] = enc;
      avg_acc[nt] += enc;
      float pv = __shfl_xor(enc, 1);     // pair (c0, c0+1) -> one dword LDS write
      if (!(lane & 1)) {
        unsigned int pk = (unsigned int)f2bf(enc) | ((unsigned int)f2bf(pv) << 16);
        *reinterpret_cast<unsigned int*>(&encT[w][q * 4 + r][nt * 16 + c0]) = pk;
      }
    }
  }

  // avg_probs partials: sum across the 4 quad-groups, then LDS accumulate
  #pragma unroll
  for (int nt = 0; nt < 32; nt++) {
    float v = avg_acc[nt];
    v += __shfl_xor(v, 16);
    v += __shfl_xor(v, 32);
    avg_acc[nt] = v;
  }
  if (lane < 16) {
    #pragma unroll
    for (int nt = 0; nt < 32; nt++) atomicAdd(&avgp[nt * 16 + lane], avg_acc[nt]);
  }
  float kw = kl_acc;                       // identical within 16-lane groups
  kw += __shfl_xor(kw, 16);
  kw += __shfl_xor(kw, 32);                // sums the 4 distinct quad-groups once
  if (lane == 0) atomicAdd(&kl_rep[wg & 31], kw);

  __syncthreads();
  for (int i = tid; i < KC; i += 128)
    atomicAdd(&avgp_rep[(size_t)(wg & 31) * KC + i], avgp[i]);

  // ================= Phase C: quantized = Enc * E (bf16 MFMA) ==================
  f32x4 accq[8];
  #pragma unroll
  for (int n2 = 0; n2 < 8; n2++) accq[n2] = {0.f, 0.f, 0.f, 0.f};
  #pragma unroll
  for (int kb = 0; kb < 16; kb++) {
    s16x8 af = *reinterpret_cast<const s16x8*>(&encT[w][c0][kb * 32 + q * 8]);
    #pragma unroll
    for (int n2 = 0; n2 < 8; n2++) {
      s16x8 b = *reinterpret_cast<const s16x8*>(ET_hi + (n2 * 16 + c0) * KC + kb * 32 + q * 8);
      accq[n2] = __builtin_amdgcn_mfma_f32_16x16x32_bf16(af, b, accq[n2], 0, 0, 0);
    }
  }
  #pragma unroll
  for (int n2 = 0; n2 < 8; n2++) {
    #pragma unroll
    for (int r = 0; r < 4; r++) {
      int grow = rowbase + q * 4 + r;
      out_q[(size_t)grow * DIM + n2 * 16 + c0] = accq[n2][r];
    }
  }
}

// ---- finalize: perplexity + KL scalars
__global__ void finalize_kernel(const float* __restrict__ avgp_rep,
                                const float* __restrict__ kl_rep,
                                float* __restrict__ d_out) {
  __shared__ float red[512];
  int t = threadIdx.x;   // 512
  float s = 0.f;
  for (int rsl = 0; rsl < 32; rsl++) s += avgp_rep[rsl * KC + t];
  float avg = s * (1.0f / (float)N_TOK);
  red[t] = avg * logf(avg + 1e-10f);
  __syncthreads();
  for (int st = 256; st > 0; st >>= 1) { if (t < st) red[t] += red[t + st]; __syncthreads(); }
  if (t == 0) {
    d_out[1 + (size_t)N_TOK * DIM] = __expf(-red[0]);   // perplexity
    float kl = 0.f;
    for (int i2 = 0; i2 < 32; i2++) kl += kl_rep[i2];
    d_out[0] = kl * (1.0f / (float)KC);                 // KL
  }
}

extern "C" void kernel_launch(void* const* d_in, const int* in_sizes, int n_in,
                              void* d_out, int out_size, void* d_ws, size_t ws_size,
                              hipStream_t stream) {
  const float* X = (const float*)d_in[0];
  const float* U = (const float*)d_in[1];
  const float* E = (const float*)d_in[2];
  float* out = (float*)d_out;

  char* ws = (char*)d_ws;
  unsigned short* E_hi   = (unsigned short*)(ws);            // 512*128*2 = 131072
  unsigned short* ET_hi  = (unsigned short*)(ws + 131072);   // 128*512*2 = 131072
  float*          normE  = (float*)(ws + 262144);            // 2048
  float*          avgp_r = (float*)(ws + 264192);            // 32*512*4 = 65536
  float*          kl_r   = (float*)(ws + 329728);            // 128

  hipMemsetAsync(ws + 264192, 0, 65536 + 128, stream);
  prep_kernel<<<512, 128, 0, stream>>>(E, E_hi, ET_hi, normE);
  vq_main<<<N_TOK / 32, 128, 0, stream>>>(X, U, E_hi, ET_hi, normE,
                                          out + 1,
                                          out + 1 + (size_t)N_TOK * DIM + 1,
                                          avgp_r, kl_r);
  finalize_kernel<<<1, 512, 0, stream>>>(avgp_r, kl_r, out);
}